// Round 1
// baseline (1766.071 us; speedup 1.0000x reference)
//
#include <hip/hip_runtime.h>

#define Q 32768
#define NR 128
#define D 512
#define C 8192

typedef __attribute__((ext_vector_type(8))) short bf16x8;
typedef __attribute__((ext_vector_type(4))) float f32x4;

__device__ __forceinline__ unsigned short f2bf(float f) {
  union { float f; unsigned u; } v; v.f = f;
  return (unsigned short)((v.u + 0x7fffu + ((v.u >> 16) & 1u)) >> 16);
}

// ---------------------------------------------------------------------------
// prep: (1) scatter old rows into queues (in-place on inputs; harness restores
// d_in each launch), (2) bf16-convert new_logits -> A2, (3) normalize
// new_embeds rows and bf16-convert -> A1.
// blocks: [0,1024) logit_queue update; [1024,2048) A2 cvt; [2048,2112)
// feat_queue update; 2112 queue_labels; [2113,2241) normalize rows.
// ---------------------------------------------------------------------------
__global__ __launch_bounds__(256) void prep_kernel(
    const float* __restrict__ old_embeds, const float* __restrict__ old_logits,
    const float* __restrict__ new_embeds, const float* __restrict__ new_logits,
    const int* __restrict__ labels, float* __restrict__ feat_queue,
    float* __restrict__ logit_queue, int* __restrict__ queue_labels,
    const int* __restrict__ headerp, unsigned short* __restrict__ A1,
    unsigned short* __restrict__ A2) {
  const int b = blockIdx.x, t = threadIdx.x;
  const int header = *headerp;
  if (b < 1024) {
    int base = b * 1024 + t * 4;
    int row = base >> 13, col = base & (C - 1);
    int qrow = (header + row) % Q;
    *(float4*)(logit_queue + (size_t)qrow * C + col) =
        *(const float4*)(old_logits + base);
  } else if (b < 2048) {
    int base = (b - 1024) * 1024 + t * 4;
    float4 v = *(const float4*)(new_logits + base);
    short4 p;
    p.x = (short)f2bf(v.x); p.y = (short)f2bf(v.y);
    p.z = (short)f2bf(v.z); p.w = (short)f2bf(v.w);
    *(short4*)(A2 + base) = p;
  } else if (b < 2112) {
    int base = (b - 2048) * 1024 + t * 4;
    int row = base >> 9, col = base & (D - 1);
    int qrow = (header + row) % Q;
    *(float4*)(feat_queue + (size_t)qrow * D + col) =
        *(const float4*)(old_embeds + base);
  } else if (b == 2112) {
    if (t < NR) queue_labels[(header + t) % Q] = labels[t];
  } else {
    int r = b - 2113;
    float x0 = new_embeds[r * D + t];
    float x1 = new_embeds[r * D + t + 256];
    float s = x0 * x0 + x1 * x1;
    #pragma unroll
    for (int off = 32; off; off >>= 1) s += __shfl_down(s, off);
    __shared__ float red[5];
    if ((t & 63) == 0) red[t >> 6] = s;
    __syncthreads();
    if (t == 0)
      red[4] = 1.0f / fmaxf(sqrtf(red[0] + red[1] + red[2] + red[3]), 1e-12f);
    __syncthreads();
    float sc = red[4];
    A1[r * D + t] = f2bf(x0 * sc);
    A1[r * D + t + 256] = f2bf(x1 * sc);
  }
}

// ---------------------------------------------------------------------------
// gemm_scores: S[128][Q] = A(bf16 [128][K]) * B(fp32 [Q][K])^T
// tile: 128(M) x 64(N), BK=64, 256 threads = 4 waves, wave w owns M rows
// [32w, 32w+32). A staged via global_load_lds(16B); B loaded fp32, converted
// to bf16 in regs, ds_write. MFMA 16x16x32 bf16, m89-verified layouts:
//   A-frag: lane l holds A[m=l&15][k=(l>>4)*8+j]; B-frag symmetric.
//   C/D: row=(l>>4)*4+reg, col=l&15.
// ---------------------------------------------------------------------------
template <int K>
__global__ __launch_bounds__(256) void gemm_scores(
    const unsigned short* __restrict__ A, const float* __restrict__ B,
    float* __restrict__ S) {
  __shared__ unsigned short As[128 * 64];  // 16 KB
  __shared__ unsigned short Bs[64 * 64];   //  8 KB
  const int t = threadIdx.x;
  const int lane = t & 63, w = t >> 6;
  const int l15 = lane & 15, l4 = lane >> 4;
  const int n0 = blockIdx.x * 64;
  f32x4 acc[2][4] = {};

  for (int k0 = 0; k0 < K; k0 += 64) {
    // A tile: 128x64 bf16 = 1024 x 16B chunks; wave-uniform LDS base + lane*16
    #pragma unroll
    for (int rep = 0; rep < 4; rep++) {
      int c = w * 256 + rep * 64 + lane;
      const unsigned short* gp = A + (size_t)(c >> 3) * K + k0 + (c & 7) * 8;
      __builtin_amdgcn_global_load_lds(
          (__attribute__((address_space(1))) void*)gp,
          (__attribute__((address_space(3))) void*)(As + (w * 256 + rep * 64) * 8),
          16, 0, 0);
    }
    // B tile: 64 rows x 64 k fp32 -> bf16
    float4 bv[4];
    #pragma unroll
    for (int rep = 0; rep < 4; rep++) {
      int c = rep * 256 + t;
      bv[rep] = *(const float4*)(B + (size_t)(n0 + (c >> 4)) * K + k0 + (c & 15) * 4);
    }
    #pragma unroll
    for (int rep = 0; rep < 4; rep++) {
      int c = rep * 256 + t;
      short4 p;
      p.x = (short)f2bf(bv[rep].x); p.y = (short)f2bf(bv[rep].y);
      p.z = (short)f2bf(bv[rep].z); p.w = (short)f2bf(bv[rep].w);
      *(short4*)&Bs[(c >> 4) * 64 + (c & 15) * 4] = p;
    }
    __syncthreads();
    #pragma unroll
    for (int kk = 0; kk < 64; kk += 32) {
      bf16x8 a0 = *(const bf16x8*)&As[(w * 32 + l15) * 64 + kk + l4 * 8];
      bf16x8 a1 = *(const bf16x8*)&As[(w * 32 + 16 + l15) * 64 + kk + l4 * 8];
      #pragma unroll
      for (int tn = 0; tn < 4; tn++) {
        bf16x8 bb = *(const bf16x8*)&Bs[(tn * 16 + l15) * 64 + kk + l4 * 8];
        acc[0][tn] = __builtin_amdgcn_mfma_f32_16x16x32_bf16(a0, bb, acc[0][tn], 0, 0, 0);
        acc[1][tn] = __builtin_amdgcn_mfma_f32_16x16x32_bf16(a1, bb, acc[1][tn], 0, 0, 0);
      }
    }
    __syncthreads();
  }
  #pragma unroll
  for (int tm = 0; tm < 2; tm++)
    #pragma unroll
    for (int tn = 0; tn < 4; tn++)
      #pragma unroll
      for (int r = 0; r < 4; r++) {
        int row = w * 32 + tm * 16 + l4 * 4 + r;
        int col = n0 + tn * 16 + l15;
        S[(size_t)row * Q + col] = acc[tm][tn][r];
      }
}

// ---------------------------------------------------------------------------
// row_reduce: one block per row. Online softmax (m,Z) for both score rows plus
// masked sums A=Σ mask*w*s, BW=Σ mask*w, CN=Σ mask; w computed on demand as
// 0.5*(old_embeds[i]·feat_queue[j]+1) (only ~5 hits/row).
// term = (A - (m+logZ)*BW)/CN.
// ---------------------------------------------------------------------------
__global__ __launch_bounds__(256) void row_reduce(
    const float* __restrict__ S1, const float* __restrict__ S2,
    const int* __restrict__ labels, const int* __restrict__ queue_labels,
    const float* __restrict__ old_embeds, const float* __restrict__ feat_queue,
    float* __restrict__ terms) {
  const int i = blockIdx.x, t = threadIdx.x;
  const int lab = labels[i];
  const float* oe = old_embeds + (size_t)i * D;
  float m1 = -__builtin_inff(), z1 = 0.f, m2 = -__builtin_inff(), z2 = 0.f;
  float a1 = 0.f, a2 = 0.f, bw = 0.f, cn = 0.f;
  for (int j = t; j < Q; j += 256) {
    float s1 = S1[(size_t)i * Q + j];
    float s2 = S2[(size_t)i * Q + j];
    if (s1 > m1) { z1 = z1 * __expf(m1 - s1) + 1.f; m1 = s1; }
    else z1 += __expf(s1 - m1);
    if (s2 > m2) { z2 = z2 * __expf(m2 - s2) + 1.f; m2 = s2; }
    else z2 += __expf(s2 - m2);
    if (queue_labels[j] == lab) {
      const float* fq = feat_queue + (size_t)j * D;
      float dot = 0.f;
      #pragma unroll 4
      for (int k = 0; k < D; k += 4) {
        float4 a = *(const float4*)(oe + k);
        float4 b4 = *(const float4*)(fq + k);
        dot += a.x * b4.x + a.y * b4.y + a.z * b4.z + a.w * b4.w;
      }
      float wgt = 0.5f * (dot + 1.f);
      a1 += wgt * s1; a2 += wgt * s2; bw += wgt; cn += 1.f;
    }
  }
  __shared__ float sm1[256], sz1[256], sm2[256], sz2[256];
  __shared__ float sa1[256], sa2[256], sbw[256], scn[256];
  sm1[t] = m1; sz1[t] = z1; sm2[t] = m2; sz2[t] = z2;
  sa1[t] = a1; sa2[t] = a2; sbw[t] = bw; scn[t] = cn;
  __syncthreads();
  if (t == 0) {
    float M1 = -__builtin_inff(), Z1 = 0.f, M2 = -__builtin_inff(), Z2 = 0.f;
    float A1s = 0.f, A2s = 0.f, BW = 0.f, CN = 0.f;
    for (int k = 0; k < 256; k++) {
      float mk = sm1[k];
      if (mk > M1) { Z1 = Z1 * __expf(M1 - mk) + sz1[k]; M1 = mk; }
      else Z1 += sz1[k] * __expf(mk - M1);
      mk = sm2[k];
      if (mk > M2) { Z2 = Z2 * __expf(M2 - mk) + sz2[k]; M2 = mk; }
      else Z2 += sz2[k] * __expf(mk - M2);
      A1s += sa1[k]; A2s += sa2[k]; BW += sbw[k]; CN += scn[k];
    }
    float lse1 = M1 + __logf(Z1);
    float lse2 = M2 + __logf(Z2);
    terms[i * 2] = (A1s - lse1 * BW) / CN;
    terms[i * 2 + 1] = (A2s - lse2 * BW) / CN;
  }
}

__global__ __launch_bounds__(128) void finalize_kernel(
    const float* __restrict__ terms, float* __restrict__ out) {
  int t = threadIdx.x;
  float t1 = terms[t * 2], t2 = terms[t * 2 + 1];
  #pragma unroll
  for (int off = 32; off; off >>= 1) {
    t1 += __shfl_down(t1, off);
    t2 += __shfl_down(t2, off);
  }
  __shared__ float r[4];
  if ((t & 63) == 0) { r[(t >> 6) * 2] = t1; r[(t >> 6) * 2 + 1] = t2; }
  __syncthreads();
  if (t == 0) {
    out[0] = -(r[0] + r[2]) / 128.0f;
    out[1] = -(r[1] + r[3]) / 128.0f;
  }
}

extern "C" void kernel_launch(void* const* d_in, const int* in_sizes, int n_in,
                              void* d_out, int out_size, void* d_ws, size_t ws_size,
                              hipStream_t stream) {
  const float* old_embeds = (const float*)d_in[0];
  const float* old_logits = (const float*)d_in[1];
  const float* new_embeds = (const float*)d_in[2];
  const float* new_logits = (const float*)d_in[3];
  const int* labels = (const int*)d_in[4];
  float* feat_queue = (float*)d_in[5];
  float* logit_queue = (float*)d_in[6];
  int* queue_labels = (int*)d_in[7];
  const int* headerp = (const int*)d_in[8];

  char* ws = (char*)d_ws;
  unsigned short* A1 = (unsigned short*)ws;                       // 128*512*2  = 128 KB
  unsigned short* A2 = (unsigned short*)(ws + (128 * 512 * 2));   // 128*8192*2 = 2 MB
  float* S1 = (float*)(ws + 128 * 512 * 2 + 128 * 8192 * 2);      // 16 MB
  float* S2 = S1 + (size_t)NR * Q;                                // 16 MB
  float* terms = S2 + (size_t)NR * Q;                             // 1 KB

  prep_kernel<<<2241, 256, 0, stream>>>(old_embeds, old_logits, new_embeds,
                                        new_logits, labels, feat_queue,
                                        logit_queue, queue_labels, headerp,
                                        A1, A2);
  gemm_scores<512><<<Q / 64, 256, 0, stream>>>(A1, feat_queue, S1);
  gemm_scores<8192><<<Q / 64, 256, 0, stream>>>(A2, logit_queue, S2);
  row_reduce<<<NR, 256, 0, stream>>>(S1, S2, labels, queue_labels, old_embeds,
                                     feat_queue, terms);
  finalize_kernel<<<1, 128, 0, stream>>>(terms, (float*)d_out);
}

// Round 2
// 1750.794 us; speedup vs baseline: 1.0087x; 1.0087x over previous
//
#include <hip/hip_runtime.h>

#define Q 32768
#define NR 128
#define D 512
#define C 8192
#define NBLK (Q / 64)   // 512 gemm blocks

typedef __attribute__((ext_vector_type(8))) short bf16x8;
typedef __attribute__((ext_vector_type(4))) float f32x4;

__device__ __forceinline__ unsigned short f2bf(float f) {
  union { float f; unsigned u; } v; v.f = f;
  return (unsigned short)((v.u + 0x7fffu + ((v.u >> 16) & 1u)) >> 16);
}

// ---------------------------------------------------------------------------
// prep: (1) scatter old rows into queues (in-place; harness restores d_in each
// launch), (2) bf16-convert new_logits -> A2, (3) normalize new_embeds rows
// and bf16-convert -> A1.
// ---------------------------------------------------------------------------
__global__ __launch_bounds__(256) void prep_kernel(
    const float* __restrict__ old_embeds, const float* __restrict__ old_logits,
    const float* __restrict__ new_embeds, const float* __restrict__ new_logits,
    const int* __restrict__ labels, float* __restrict__ feat_queue,
    float* __restrict__ logit_queue, int* __restrict__ queue_labels,
    const int* __restrict__ headerp, unsigned short* __restrict__ A1,
    unsigned short* __restrict__ A2) {
  const int b = blockIdx.x, t = threadIdx.x;
  const int header = *headerp;
  if (b < 1024) {
    int base = b * 1024 + t * 4;
    int row = base >> 13, col = base & (C - 1);
    int qrow = (header + row) % Q;
    *(float4*)(logit_queue + (size_t)qrow * C + col) =
        *(const float4*)(old_logits + base);
  } else if (b < 2048) {
    int base = (b - 1024) * 1024 + t * 4;
    float4 v = *(const float4*)(new_logits + base);
    short4 p;
    p.x = (short)f2bf(v.x); p.y = (short)f2bf(v.y);
    p.z = (short)f2bf(v.z); p.w = (short)f2bf(v.w);
    *(short4*)(A2 + base) = p;
  } else if (b < 2112) {
    int base = (b - 2048) * 1024 + t * 4;
    int row = base >> 9, col = base & (D - 1);
    int qrow = (header + row) % Q;
    *(float4*)(feat_queue + (size_t)qrow * D + col) =
        *(const float4*)(old_embeds + base);
  } else if (b == 2112) {
    if (t < NR) queue_labels[(header + t) % Q] = labels[t];
  } else {
    int r = b - 2113;
    float x0 = new_embeds[r * D + t];
    float x1 = new_embeds[r * D + t + 256];
    float s = x0 * x0 + x1 * x1;
    #pragma unroll
    for (int off = 32; off; off >>= 1) s += __shfl_down(s, off);
    __shared__ float red[5];
    if ((t & 63) == 0) red[t >> 6] = s;
    __syncthreads();
    if (t == 0)
      red[4] = 1.0f / fmaxf(sqrtf(red[0] + red[1] + red[2] + red[3]), 1e-12f);
    __syncthreads();
    float sc = red[4];
    A1[r * D + t] = f2bf(x0 * sc);
    A1[r * D + t + 256] = f2bf(x1 * sc);
  }
}

// ---------------------------------------------------------------------------
// gemm_fused: S = A(bf16 [128][K]) * B(fp32 [Q][K])^T, fused per-block
// softmax/mask partials (no S materialization).
// tile 128(M) x 64(N), BK=64, 4 waves; wave w owns rows [32w,32w+32).
// Pipelined: double-buffered LDS A (global_load_lds 16B) + B (regs->cvt->LDS),
// next-tile loads issued before MFMA phase, one barrier per K-iter.
// MFMA 16x16x32 bf16, m89 layouts: C/D row=(l>>4)*4+reg, col=l&15.
// Epilogue partials per row over the block's 64 cols:
//   m=max(s), z=sum exp(s-m), a=sum_{hit} w*s  (+ bw=sum w, cn=#hits if WW)
// where hit = (queue_labels[col]==labels[row]), w=0.5*(old_e[row].fq[col]+1).
// ---------------------------------------------------------------------------
template <int K, bool WW>
__global__ __launch_bounds__(256) void gemm_fused(
    const unsigned short* __restrict__ A, const float* __restrict__ B,
    const int* __restrict__ labels, const int* __restrict__ queue_labels,
    const float* __restrict__ old_embeds, const float* __restrict__ feat_queue,
    float* __restrict__ Pm, float* __restrict__ Pz, float* __restrict__ Pa,
    float* __restrict__ Pbw, float* __restrict__ Pcn) {
  __shared__ unsigned short As[2][128 * 64];  // 2 x 16 KB
  __shared__ unsigned short Bs[2][64 * 64];   // 2 x  8 KB
  const int t = threadIdx.x;
  const int lane = t & 63, w = t >> 6;
  const int l15 = lane & 15, l4 = lane >> 4;
  const int n0 = blockIdx.x * 64;
  f32x4 acc[2][4] = {};

  // ---- prologue: stage tile 0 ----
  #pragma unroll
  for (int rep = 0; rep < 4; rep++) {
    int c = w * 256 + rep * 64 + lane;
    const unsigned short* gp = A + (size_t)(c >> 3) * K + (c & 7) * 8;
    __builtin_amdgcn_global_load_lds(
        (__attribute__((address_space(1))) void*)gp,
        (__attribute__((address_space(3))) void*)(&As[0][0] + (w * 256 + rep * 64) * 8),
        16, 0, 0);
  }
  {
    float4 bv[4];
    #pragma unroll
    for (int rep = 0; rep < 4; rep++) {
      int c = rep * 256 + t;
      bv[rep] = *(const float4*)(B + (size_t)(n0 + (c >> 4)) * K + (c & 15) * 4);
    }
    #pragma unroll
    for (int rep = 0; rep < 4; rep++) {
      int c = rep * 256 + t;
      short4 p;
      p.x = (short)f2bf(bv[rep].x); p.y = (short)f2bf(bv[rep].y);
      p.z = (short)f2bf(bv[rep].z); p.w = (short)f2bf(bv[rep].w);
      *(short4*)&Bs[0][(c >> 4) * 64 + (c & 15) * 4] = p;
    }
  }
  __syncthreads();

  // ---- pipelined K loop ----
  for (int k0 = 0; k0 < K; k0 += 64) {
    const int buf = (k0 >> 6) & 1, nbuf = buf ^ 1;
    const bool more = (k0 + 64 < K);
    float4 bv[4];
    if (more) {
      // issue next A tile -> LDS (async) and next B tile -> regs
      #pragma unroll
      for (int rep = 0; rep < 4; rep++) {
        int c = w * 256 + rep * 64 + lane;
        const unsigned short* gp = A + (size_t)(c >> 3) * K + (k0 + 64) + (c & 7) * 8;
        __builtin_amdgcn_global_load_lds(
            (__attribute__((address_space(1))) void*)gp,
            (__attribute__((address_space(3))) void*)(&As[nbuf][0] + (w * 256 + rep * 64) * 8),
            16, 0, 0);
      }
      #pragma unroll
      for (int rep = 0; rep < 4; rep++) {
        int c = rep * 256 + t;
        bv[rep] = *(const float4*)(B + (size_t)(n0 + (c >> 4)) * K + (k0 + 64) + (c & 15) * 4);
      }
    }
    // MFMA on current buffers (loads above stay in flight)
    #pragma unroll
    for (int kk = 0; kk < 64; kk += 32) {
      bf16x8 a0 = *(const bf16x8*)&As[buf][(w * 32 + l15) * 64 + kk + l4 * 8];
      bf16x8 a1 = *(const bf16x8*)&As[buf][(w * 32 + 16 + l15) * 64 + kk + l4 * 8];
      #pragma unroll
      for (int tn = 0; tn < 4; tn++) {
        bf16x8 bb = *(const bf16x8*)&Bs[buf][(tn * 16 + l15) * 64 + kk + l4 * 8];
        acc[0][tn] = __builtin_amdgcn_mfma_f32_16x16x32_bf16(a0, bb, acc[0][tn], 0, 0, 0);
        acc[1][tn] = __builtin_amdgcn_mfma_f32_16x16x32_bf16(a1, bb, acc[1][tn], 0, 0, 0);
      }
    }
    if (more) {
      #pragma unroll
      for (int rep = 0; rep < 4; rep++) {
        int c = rep * 256 + t;
        short4 p;
        p.x = (short)f2bf(bv[rep].x); p.y = (short)f2bf(bv[rep].y);
        p.z = (short)f2bf(bv[rep].z); p.w = (short)f2bf(bv[rep].w);
        *(short4*)&Bs[nbuf][(c >> 4) * 64 + (c & 15) * 4] = p;
      }
    }
    __syncthreads();
  }

  // ---- fused epilogue: per-row partials over this block's 64 columns ----
  int qlab[4];
  #pragma unroll
  for (int tn = 0; tn < 4; tn++) qlab[tn] = queue_labels[n0 + tn * 16 + l15];

  #pragma unroll
  for (int tm = 0; tm < 2; tm++) {
    #pragma unroll
    for (int r = 0; r < 4; r++) {
      const int row = w * 32 + tm * 16 + l4 * 4 + r;
      const int lab = labels[row];
      float m = acc[tm][0][r];
      #pragma unroll
      for (int tn = 1; tn < 4; tn++) m = fmaxf(m, acc[tm][tn][r]);
      float z = 0.f, a = 0.f, bwv = 0.f, cnv = 0.f;
      #pragma unroll
      for (int tn = 0; tn < 4; tn++) {
        float s = acc[tm][tn][r];
        z += __expf(s - m);
        if (qlab[tn] == lab) {
          const float* oe = old_embeds + (size_t)row * D;
          const float* fq = feat_queue + (size_t)(n0 + tn * 16 + l15) * D;
          float dot = 0.f;
          #pragma unroll 4
          for (int k = 0; k < D; k += 4) {
            float4 av = *(const float4*)(oe + k);
            float4 bv4 = *(const float4*)(fq + k);
            dot += av.x * bv4.x + av.y * bv4.y + av.z * bv4.z + av.w * bv4.w;
          }
          float wt = 0.5f * (dot + 1.f);
          a += wt * s; bwv += wt; cnv += 1.f;
        }
      }
      // reduce over the 16-lane col group (l15)
      #pragma unroll
      for (int d = 1; d < 16; d <<= 1) {
        float mo = __shfl_xor(m, d), zo = __shfl_xor(z, d);
        float M = fmaxf(m, mo);
        z = z * __expf(m - M) + zo * __expf(mo - M);
        m = M;
        a += __shfl_xor(a, d);
        if (WW) { bwv += __shfl_xor(bwv, d); cnv += __shfl_xor(cnv, d); }
      }
      if (l15 == 0) {
        const size_t idx = (size_t)row * NBLK + blockIdx.x;
        Pm[idx] = m; Pz[idx] = z; Pa[idx] = a;
        if (WW) { Pbw[idx] = bwv; Pcn[idx] = cnv; }
      }
    }
  }
}

// ---------------------------------------------------------------------------
// combine: one wave per row; online-merge 512 partials, compute terms.
// ---------------------------------------------------------------------------
__global__ __launch_bounds__(64) void combine_kernel(
    const float* __restrict__ Pm1, const float* __restrict__ Pz1,
    const float* __restrict__ Pa1, const float* __restrict__ Pm2,
    const float* __restrict__ Pz2, const float* __restrict__ Pa2,
    const float* __restrict__ Pbw, const float* __restrict__ Pcn,
    float* __restrict__ terms) {
  const int row = blockIdx.x, l = threadIdx.x;
  float m1 = -__builtin_inff(), z1 = 0.f, a1 = 0.f;
  float m2 = -__builtin_inff(), z2 = 0.f, a2 = 0.f;
  float bw = 0.f, cn = 0.f;
  for (int b = l; b < NBLK; b += 64) {
    const size_t idx = (size_t)row * NBLK + b;
    float mo = Pm1[idx], zo = Pz1[idx];
    float M = fmaxf(m1, mo);
    z1 = z1 * __expf(m1 - M) + zo * __expf(mo - M); m1 = M;
    a1 += Pa1[idx];
    mo = Pm2[idx]; zo = Pz2[idx];
    M = fmaxf(m2, mo);
    z2 = z2 * __expf(m2 - M) + zo * __expf(mo - M); m2 = M;
    a2 += Pa2[idx];
    bw += Pbw[idx]; cn += Pcn[idx];
  }
  #pragma unroll
  for (int d = 1; d < 64; d <<= 1) {
    float mo = __shfl_xor(m1, d), zo = __shfl_xor(z1, d);
    float M = fmaxf(m1, mo);
    z1 = z1 * __expf(m1 - M) + zo * __expf(mo - M); m1 = M;
    mo = __shfl_xor(m2, d); zo = __shfl_xor(z2, d);
    M = fmaxf(m2, mo);
    z2 = z2 * __expf(m2 - M) + zo * __expf(mo - M); m2 = M;
    a1 += __shfl_xor(a1, d); a2 += __shfl_xor(a2, d);
    bw += __shfl_xor(bw, d); cn += __shfl_xor(cn, d);
  }
  if (l == 0) {
    terms[row * 2]     = (a1 - (m1 + __logf(z1)) * bw) / cn;
    terms[row * 2 + 1] = (a2 - (m2 + __logf(z2)) * bw) / cn;
  }
}

__global__ __launch_bounds__(128) void finalize_kernel(
    const float* __restrict__ terms, float* __restrict__ out) {
  int t = threadIdx.x;
  float t1 = terms[t * 2], t2 = terms[t * 2 + 1];
  #pragma unroll
  for (int off = 32; off; off >>= 1) {
    t1 += __shfl_down(t1, off);
    t2 += __shfl_down(t2, off);
  }
  __shared__ float r[4];
  if ((t & 63) == 0) { r[(t >> 6) * 2] = t1; r[(t >> 6) * 2 + 1] = t2; }
  __syncthreads();
  if (t == 0) {
    out[0] = -(r[0] + r[2]) / 128.0f;
    out[1] = -(r[1] + r[3]) / 128.0f;
  }
}

extern "C" void kernel_launch(void* const* d_in, const int* in_sizes, int n_in,
                              void* d_out, int out_size, void* d_ws, size_t ws_size,
                              hipStream_t stream) {
  const float* old_embeds = (const float*)d_in[0];
  const float* old_logits = (const float*)d_in[1];
  const float* new_embeds = (const float*)d_in[2];
  const float* new_logits = (const float*)d_in[3];
  const int* labels = (const int*)d_in[4];
  float* feat_queue = (float*)d_in[5];
  float* logit_queue = (float*)d_in[6];
  int* queue_labels = (int*)d_in[7];
  const int* headerp = (const int*)d_in[8];

  char* ws = (char*)d_ws;
  unsigned short* A1 = (unsigned short*)ws;                      // 128 KB
  unsigned short* A2 = (unsigned short*)(ws + 128 * 512 * 2);    // 2 MB
  float* P = (float*)(ws + 128 * 512 * 2 + 128 * 8192 * 2);
  const size_t PSZ = (size_t)NR * NBLK;                          // 64K floats each
  float* Pm1 = P;            float* Pz1 = P + PSZ;      float* Pa1 = P + 2 * PSZ;
  float* Pm2 = P + 3 * PSZ;  float* Pz2 = P + 4 * PSZ;  float* Pa2 = P + 5 * PSZ;
  float* Pbw = P + 6 * PSZ;  float* Pcn = P + 7 * PSZ;
  float* terms = P + 8 * PSZ;

  prep_kernel<<<2241, 256, 0, stream>>>(old_embeds, old_logits, new_embeds,
                                        new_logits, labels, feat_queue,
                                        logit_queue, queue_labels, headerp,
                                        A1, A2);
  gemm_fused<512, true><<<NBLK, 256, 0, stream>>>(
      A1, feat_queue, labels, queue_labels, old_embeds, feat_queue,
      Pm1, Pz1, Pa1, Pbw, Pcn);
  gemm_fused<8192, false><<<NBLK, 256, 0, stream>>>(
      A2, logit_queue, labels, queue_labels, old_embeds, feat_queue,
      Pm2, Pz2, Pa2, nullptr, nullptr);
  combine_kernel<<<NR, 64, 0, stream>>>(Pm1, Pz1, Pa1, Pm2, Pz2, Pa2,
                                        Pbw, Pcn, terms);
  finalize_kernel<<<1, 128, 0, stream>>>(terms, (float*)d_out);
}